// Round 5
// baseline (364.166 us; speedup 1.0000x reference)
//
#include <hip/hip_runtime.h>
#include <hip/hip_cooperative_groups.h>
#include <stdint.h>

namespace cg = cooperative_groups;

#define NR 16384
#define KI 256
#define MO 128
#define ALPHA 0.01f
#define CH 32             // rows per chunk
#define NCH (NR / CH)     // 512 chunks
#define RB 8              // i-keys per thread in rank
#define JT 256            // j-keys staged in LDS per block
#define NJ (NR / JT)      // 64 j-chunks
#define NB 512            // cooperative grid blocks

typedef unsigned long long u64;

// sortable key: monotone float order, index tie-break (rank is a bijection)
static __device__ __forceinline__ u64 sort_key(float f, int j) {
    unsigned u = __float_as_uint(f);
    u ^= ((unsigned)((int)u >> 31)) | 0x80000000u;
    return (((u64)u) << 14) | (unsigned)(j & 0x3FFF);
}

// ---------------- K1: h = x@W^T (64x128 tile, 256 thr, 4x8 micro) + fused s1,s2,keys (R3-proven) ----------------
__global__ __launch_bounds__(256) void k_gemm_fused(const float* __restrict__ x,
                                                    const float* __restrict__ w,
                                                    const float* __restrict__ a1,
                                                    const float* __restrict__ a2,
                                                    float* __restrict__ h,
                                                    float* __restrict__ s1,
                                                    float* __restrict__ s2,
                                                    u64* __restrict__ keys) {
    __shared__ float As[16][68];
    __shared__ float Bs[16][132];
    const int t = threadIdx.x;
    const int rowBase = blockIdx.x * 64;
    const int tx = t & 15;
    const int ty = t >> 4;
    const int ar = t >> 2, ak = (t & 3) << 2;
    const int br = t >> 1, bk = (t & 1) << 3;
    float acc[4][8] = {};
    for (int k0 = 0; k0 < KI; k0 += 16) {
        float4 av  = *(const float4*)&x[(rowBase + ar) * KI + k0 + ak];
        float4 bv0 = *(const float4*)&w[br * KI + k0 + bk];
        float4 bv1 = *(const float4*)&w[br * KI + k0 + bk + 4];
        __syncthreads();
        As[ak + 0][ar] = av.x; As[ak + 1][ar] = av.y;
        As[ak + 2][ar] = av.z; As[ak + 3][ar] = av.w;
        Bs[bk + 0][br] = bv0.x; Bs[bk + 1][br] = bv0.y;
        Bs[bk + 2][br] = bv0.z; Bs[bk + 3][br] = bv0.w;
        Bs[bk + 4][br] = bv1.x; Bs[bk + 5][br] = bv1.y;
        Bs[bk + 6][br] = bv1.z; Bs[bk + 7][br] = bv1.w;
        __syncthreads();
#pragma unroll
        for (int k = 0; k < 16; ++k) {
            float4 a4 = *(const float4*)&As[k][ty << 2];
            float4 b0 = *(const float4*)&Bs[k][tx << 3];
            float4 b1 = *(const float4*)&Bs[k][(tx << 3) + 4];
            float a[4] = {a4.x, a4.y, a4.z, a4.w};
            float b[8] = {b0.x, b0.y, b0.z, b0.w, b1.x, b1.y, b1.z, b1.w};
#pragma unroll
            for (int i = 0; i < 4; ++i)
#pragma unroll
                for (int j = 0; j < 8; ++j)
                    acc[i][j] = fmaf(a[i], b[j], acc[i][j]);
        }
    }
#pragma unroll
    for (int i = 0; i < 4; ++i) {
        float4 st0 = {acc[i][0], acc[i][1], acc[i][2], acc[i][3]};
        float4 st1 = {acc[i][4], acc[i][5], acc[i][6], acc[i][7]};
        float* hp = &h[(size_t)(rowBase + (ty << 2) + i) * MO + (tx << 3)];
        *(float4*)hp = st0;
        *(float4*)(hp + 4) = st1;
    }
    float4 a1lo = *(const float4*)&a1[tx << 3];
    float4 a1hi = *(const float4*)&a1[(tx << 3) + 4];
    float4 a2lo = *(const float4*)&a2[tx << 3];
    float4 a2hi = *(const float4*)&a2[(tx << 3) + 4];
    float a1v[8] = {a1lo.x, a1lo.y, a1lo.z, a1lo.w, a1hi.x, a1hi.y, a1hi.z, a1hi.w};
    float a2v[8] = {a2lo.x, a2lo.y, a2lo.z, a2lo.w, a2hi.x, a2hi.y, a2hi.z, a2hi.w};
#pragma unroll
    for (int r = 0; r < 4; ++r) {
        float p1 = 0.f, p2 = 0.f;
#pragma unroll
        for (int c = 0; c < 8; ++c) {
            p1 = fmaf(acc[r][c], a1v[c], p1);
            p2 = fmaf(acc[r][c], a2v[c], p2);
        }
#pragma unroll
        for (int off = 8; off; off >>= 1) {
            p1 += __shfl_xor(p1, off, 64);
            p2 += __shfl_xor(p2, off, 64);
        }
        if (tx == 0) {
            int row = rowBase + (ty << 2) + r;
            s1[row] = p1;
            s2[row] = p2;
            keys[row] = sort_key(p1, row);
        }
    }
}

// ---------------- K2: everything else, fused via cooperative grid sync ----------------
__global__ __launch_bounds__(256, 2) void k_post(const u64* __restrict__ keys,
                                                 const float* __restrict__ s1,
                                                 const float* __restrict__ s2,
                                                 const float* __restrict__ h,
                                                 float* __restrict__ s1s,
                                                 int* __restrict__ perm,
                                                 int* __restrict__ kidx,
                                                 float* __restrict__ psumH,
                                                 float* __restrict__ psumSH,
                                                 float* __restrict__ cSufH,
                                                 float* __restrict__ cSufS,
                                                 float2* __restrict__ SHS,
                                                 int* __restrict__ rankPart,
                                                 float* __restrict__ out) {
    cg::grid_group grid = cg::this_grid();
    const int b = blockIdx.x;
    const int t = threadIdx.x;

    __shared__ u64 sk[JT];                 // P0
    __shared__ float bH[NCH], bS[NCH];     // P3 scan
    __shared__ int pi[CH];                 // P2/P4
    __shared__ float ss[CH];
    __shared__ float rH[256], rS[256];     // P2 reduce / P4 publish

    // ---- P0: rank partials (bi = b&7 -> 2048 i's, bj = b>>3 -> 256 j's) ----
    {
        const int ibase = (b & 7) * (256 * RB);
        const int jbase = (b >> 3) * JT;
        sk[t] = keys[jbase + t];
        u64 ki[RB];
#pragma unroll
        for (int k = 0; k < RB; ++k) ki[k] = keys[ibase + k * 256 + t];
        int cnt[RB] = {};
        __syncthreads();
#pragma unroll 4
        for (int jj = 0; jj < JT; ++jj) {
            u64 kj = sk[jj];               // uniform addr -> LDS broadcast
#pragma unroll
            for (int k = 0; k < RB; ++k)
                cnt[k] += (kj < ki[k]) ? 1 : 0;
        }
#pragma unroll
        for (int k = 0; k < RB; ++k)
            rankPart[(b >> 3) * NR + ibase + k * 256 + t] = cnt[k];
    }
    grid.sync();

    // ---- P1: scatter into sorted order (blocks 0..63) ----
    if (b < 64) {
        int i = b * 256 + t;
        int r = 0;
        for (int p = 0; p < NJ; ++p) r += rankPart[p * NR + i];
        s1s[r] = s1[i];
        perm[r] = i;
    }
    grid.sync();

    // ---- P2: per-chunk partial sums (block = chunk, halves split rows) ----
    {
        const int c = t & 127, g = t >> 7, q = b;
        if (t < CH) { pi[t] = perm[q * CH + t]; ss[t] = s1s[q * CH + t]; }
        __syncthreads();
        float pH = 0.f, pS = 0.f;
#pragma unroll
        for (int m = 0; m < 16; ++m) {
            int row = g * 16 + m;
            float v = h[(size_t)pi[row] * MO + c];
            pH += v;
            pS = fmaf(ss[row], v, pS);
        }
        rH[t] = pH; rS[t] = pS;
        __syncthreads();
        if (g == 0) {
            psumH[q * MO + c]  = rH[c] + rH[c + 128];
            psumSH[q * MO + c] = rS[c] + rS[c + 128];
        }
    }
    grid.sync();

    // ---- P3: suffix scan over chunks (blocks 0..127) || kidx binary search (blocks 128..191) ----
    if (b < 128) {
        const int c = b;
        const int q0 = t, q1 = t + 256;
        float vH0 = psumH[q0 * MO + c], vS0 = psumSH[q0 * MO + c];
        float vH1 = psumH[q1 * MO + c], vS1 = psumSH[q1 * MO + c];
        bH[q0] = vH0; bS[q0] = vS0;
        bH[q1] = vH1; bS[q1] = vS1;
        __syncthreads();
#pragma unroll
        for (int off = 1; off < NCH; off <<= 1) {
            float aH0 = 0.f, aS0 = 0.f, aH1 = 0.f, aS1 = 0.f;
            if (q0 + off < NCH) { aH0 = bH[q0 + off]; aS0 = bS[q0 + off]; }
            if (q1 + off < NCH) { aH1 = bH[q1 + off]; aS1 = bS[q1 + off]; }
            __syncthreads();
            bH[q0] += aH0; bS[q0] += aS0;
            bH[q1] += aH1; bS[q1] += aS1;
            __syncthreads();
        }
        cSufH[q0 * MO + c] = bH[q0] - vH0;   // exclusive suffix (chunks > q)
        cSufS[q0 * MO + c] = bS[q0] - vS0;
        cSufH[q1 * MO + c] = bH[q1] - vH1;
        cSufS[q1 * MO + c] = bS[q1] - vS1;
        if (b == 0 && t < 128) SHS[(size_t)NR * MO + t] = make_float2(0.f, 0.f);
    } else if (b < 192) {
        int i = (b - 128) * 256 + t;
        float tv = -s2[i];
        int lo = 0, hi = NR;
        while (lo < hi) {
            int mid = (lo + hi) >> 1;
            if (s1s[mid] < tv) lo = mid + 1; else hi = mid;
        }
        kidx[i] = lo;
    }
    grid.sync();

    // ---- P4: materialize interleaved suffix arrays SHS[k] = (SH, SSH) ----
    {
        const int c = t & 127, g = t >> 7, q = b;
        if (t < CH) { pi[t] = perm[q * CH + t]; ss[t] = s1s[q * CH + t]; }
        __syncthreads();
        float v[16];
#pragma unroll
        for (int m = 0; m < 16; ++m)
            v[m] = h[(size_t)pi[g * 16 + m] * MO + c];
        float runH, runS;
        if (g == 1) {
            runH = cSufH[q * MO + c]; runS = cSufS[q * MO + c];
#pragma unroll
            for (int m = 15; m >= 0; --m) {
                runH += v[m];
                runS = fmaf(ss[16 + m], v[m], runS);
                SHS[(size_t)(q * CH + 16 + m) * MO + c] = make_float2(runH, runS);
            }
            rH[c] = runH; rS[c] = runS;
        }
        __syncthreads();
        if (g == 0) {
            runH = rH[c]; runS = rS[c];
#pragma unroll
            for (int m = 15; m >= 0; --m) {
                runH += v[m];
                runS = fmaf(ss[m], v[m], runS);
                SHS[(size_t)(q * CH + m) * MO + c] = make_float2(runH, runS);
            }
        }
    }
    grid.sync();

    // ---- P5: out[i][c] (block covers 32 rows; halves take 16 rows each) ----
    {
        const int c = t & 127, g = t >> 7;
        float2 tot = SHS[c];   // suffix from row 0 = totals
#pragma unroll 4
        for (int r = 0; r < 16; ++r) {
            int i = b * 32 + g * 16 + r;
            float s2v = s2[i];
            int k = kidx[i];
            float2 sv = SHS[(size_t)k * MO + c];
            out[(size_t)i * MO + c] =
                ALPHA * fmaf(s2v, tot.x, tot.y) + (1.f - ALPHA) * fmaf(s2v, sv.x, sv.y);
        }
    }
}

extern "C" void kernel_launch(void* const* d_in, const int* in_sizes, int n_in,
                              void* d_out, int out_size, void* d_ws, size_t ws_size,
                              hipStream_t stream) {
    const float* x  = (const float*)d_in[0];
    const float* w  = (const float*)d_in[1];
    const float* a1 = (const float*)d_in[2];
    const float* a2 = (const float*)d_in[3];
    float* out = (float*)d_out;

    float*  ws     = (float*)d_ws;
    float*  h      = ws;                                // NR*MO
    float2* SHS    = (float2*)(h + (size_t)NR * MO);    // (NR+1)*MO float2
    float*  s1     = (float*)(SHS + (size_t)(NR + 1) * MO);
    float*  s2     = s1 + NR;
    float*  s1s    = s2 + NR;
    u64*    keys   = (u64*)(s1s + NR);                  // NR u64
    int*    perm   = (int*)(keys + NR);
    int*    kidx   = perm + NR;
    float*  psumH  = (float*)(kidx + NR);               // NCH*MO
    float*  psumSH = psumH + NCH * MO;
    float*  cSufH  = psumSH + NCH * MO;
    float*  cSufS  = cSufH + NCH * MO;
    int*    rankPart = (int*)SHS;   // NJ*NR*4 = 4 MB aliases SHS (16.8 MB); dead before SHS written

    k_gemm_fused<<<NR / 64, 256, 0, stream>>>(x, w, a1, a2, h, s1, s2, keys);

    const u64* keys_c = keys; const float* s1_c = s1; const float* s2_c = s2;
    const float* h_c = h;
    void* args[] = {
        (void*)&keys_c, (void*)&s1_c, (void*)&s2_c, (void*)&h_c,
        (void*)&s1s, (void*)&perm, (void*)&kidx,
        (void*)&psumH, (void*)&psumSH, (void*)&cSufH, (void*)&cSufS,
        (void*)&SHS, (void*)&rankPart, (void*)&out
    };
    hipLaunchCooperativeKernel((const void*)k_post, dim3(NB), dim3(256), args, 0, stream);
}

// Round 6
// 145.703 us; speedup vs baseline: 2.4994x; 2.4994x over previous
//
#include <hip/hip_runtime.h>
#include <stdint.h>

#define NR 16384
#define KI 256
#define MO 128
#define ALPHA 0.01f
#define CH 32             // rows per chunk
#define NCH (NR / CH)     // 512 chunks
#define RB 8              // i-keys per thread in k_rank
#define JT 256            // j-keys staged in LDS per block
#define NJ (NR / JT)      // 64 j-chunks

typedef unsigned long long u64;

// sortable key: monotone float order, index tie-break (rank is a bijection)
static __device__ __forceinline__ u64 sort_key(float f, int j) {
    unsigned u = __float_as_uint(f);
    u ^= ((unsigned)((int)u >> 31)) | 0x80000000u;
    return (((u64)u) << 14) | (unsigned)(j & 0x3FFF);
}

// ---------------- K1: h = x@W^T (32x128 tile, 512 blocks = 2/CU) + fused s1,s2,keys ----------------
__global__ __launch_bounds__(256) void k_gemm_fused(const float* __restrict__ x,
                                                    const float* __restrict__ w,
                                                    const float* __restrict__ a1,
                                                    const float* __restrict__ a2,
                                                    float* __restrict__ h,
                                                    float* __restrict__ s1,
                                                    float* __restrict__ s2,
                                                    u64* __restrict__ keys) {
    __shared__ float As[16][36];    // [k][row 0..31]
    __shared__ float Bs[16][132];   // [k][col 0..127]
    const int t = threadIdx.x;
    const int rowBase = blockIdx.x * 32;
    const int tx = t & 15;          // col group: cols tx*8..tx*8+7
    const int ty = t >> 4;          // rows ty*2, ty*2+1
    const int ar = t >> 2, ak = (t & 3) << 2;   // A staging (t<128): row ar, k ak..ak+3
    const int br = t >> 1, bk = (t & 1) << 3;   // B staging: col br, k bk..bk+7
    float acc[2][8] = {};
    for (int k0 = 0; k0 < KI; k0 += 16) {
        float4 av = {};
        if (t < 128) av = *(const float4*)&x[(rowBase + ar) * KI + k0 + ak];
        float4 bv0 = *(const float4*)&w[br * KI + k0 + bk];
        float4 bv1 = *(const float4*)&w[br * KI + k0 + bk + 4];
        __syncthreads();
        if (t < 128) {
            As[ak + 0][ar] = av.x; As[ak + 1][ar] = av.y;
            As[ak + 2][ar] = av.z; As[ak + 3][ar] = av.w;
        }
        Bs[bk + 0][br] = bv0.x; Bs[bk + 1][br] = bv0.y;
        Bs[bk + 2][br] = bv0.z; Bs[bk + 3][br] = bv0.w;
        Bs[bk + 4][br] = bv1.x; Bs[bk + 5][br] = bv1.y;
        Bs[bk + 6][br] = bv1.z; Bs[bk + 7][br] = bv1.w;
        __syncthreads();
#pragma unroll
        for (int k = 0; k < 16; ++k) {
            float2 a2v_ = *(const float2*)&As[k][ty << 1];
            float4 b0 = *(const float4*)&Bs[k][tx << 3];
            float4 b1 = *(const float4*)&Bs[k][(tx << 3) + 4];
            float b[8] = {b0.x, b0.y, b0.z, b0.w, b1.x, b1.y, b1.z, b1.w};
#pragma unroll
            for (int j = 0; j < 8; ++j) {
                acc[0][j] = fmaf(a2v_.x, b[j], acc[0][j]);
                acc[1][j] = fmaf(a2v_.y, b[j], acc[1][j]);
            }
        }
    }
#pragma unroll
    for (int r = 0; r < 2; ++r) {
        float4 st0 = {acc[r][0], acc[r][1], acc[r][2], acc[r][3]};
        float4 st1 = {acc[r][4], acc[r][5], acc[r][6], acc[r][7]};
        float* hp = &h[(size_t)(rowBase + (ty << 1) + r) * MO + (tx << 3)];
        *(float4*)hp = st0;
        *(float4*)(hp + 4) = st1;
    }
    float4 a1lo = *(const float4*)&a1[tx << 3];
    float4 a1hi = *(const float4*)&a1[(tx << 3) + 4];
    float4 a2lo = *(const float4*)&a2[tx << 3];
    float4 a2hi = *(const float4*)&a2[(tx << 3) + 4];
    float a1v[8] = {a1lo.x, a1lo.y, a1lo.z, a1lo.w, a1hi.x, a1hi.y, a1hi.z, a1hi.w};
    float a2v[8] = {a2lo.x, a2lo.y, a2lo.z, a2lo.w, a2hi.x, a2hi.y, a2hi.z, a2hi.w};
#pragma unroll
    for (int r = 0; r < 2; ++r) {
        float p1 = 0.f, p2 = 0.f;
#pragma unroll
        for (int c = 0; c < 8; ++c) {
            p1 = fmaf(acc[r][c], a1v[c], p1);
            p2 = fmaf(acc[r][c], a2v[c], p2);
        }
#pragma unroll
        for (int off = 8; off; off >>= 1) {   // reduce over tx (lane bits 0..3)
            p1 += __shfl_xor(p1, off, 64);
            p2 += __shfl_xor(p2, off, 64);
        }
        if (tx == 0) {
            int row = rowBase + (ty << 1) + r;
            s1[row] = p1;
            s2[row] = p2;
            keys[row] = sort_key(p1, row);
        }
    }
}

// ---------------- K2: rank partials — LDS-broadcast j-keys, 8 i-keys/thread (R3-proven) ----------------
__global__ __launch_bounds__(256) void k_rank(const u64* __restrict__ keys,
                                              int* __restrict__ rankPart) {
    __shared__ u64 sk[JT];
    const int t = threadIdx.x;
    const int ibase = blockIdx.x * (256 * RB);
    const int jbase = blockIdx.y * JT;
    sk[t] = keys[jbase + t];
    u64 ki[RB];
#pragma unroll
    for (int k = 0; k < RB; ++k) ki[k] = keys[ibase + k * 256 + t];
    int cnt[RB] = {};
    __syncthreads();
#pragma unroll 4
    for (int jj = 0; jj < JT; ++jj) {
        u64 kj = sk[jj];                 // uniform addr -> LDS broadcast, conflict-free
#pragma unroll
        for (int k = 0; k < RB; ++k)
            cnt[k] += (kj < ki[k]) ? 1 : 0;
    }
#pragma unroll
    for (int k = 0; k < RB; ++k)
        rankPart[blockIdx.y * NR + ibase + k * 256 + t] = cnt[k];
}

// ---------------- K3: sum partials, scatter into sorted order (R3-proven) ----------------
__global__ __launch_bounds__(256) void k_scatter(const float* __restrict__ s1,
                                                 const int* __restrict__ rankPart,
                                                 float* __restrict__ s1s,
                                                 int* __restrict__ perm) {
    int i = blockIdx.x * 256 + threadIdx.x;
    int r = 0;
#pragma unroll
    for (int p = 0; p < NJ; ++p) r += rankPart[p * NR + i];
    s1s[r] = s1[i];
    perm[r] = i;
}

// ---------------- K4: per-chunk partial sums of sorted h, s1*h (R3-proven) ----------------
__global__ __launch_bounds__(128) void k_psum(const float* __restrict__ h,
                                              const int* __restrict__ perm,
                                              const float* __restrict__ s1s,
                                              float* __restrict__ psumH,
                                              float* __restrict__ psumSH) {
    __shared__ int pi[CH];
    __shared__ float ss[CH];
    const int c = threadIdx.x, q = blockIdx.x;
    if (c < CH) { pi[c] = perm[q * CH + c]; ss[c] = s1s[q * CH + c]; }
    __syncthreads();
    float sh = 0.f, sv = 0.f;
#pragma unroll 4
    for (int m = 0; m < CH; ++m) {
        float v = h[(size_t)pi[m] * MO + c];
        sh += v;
        sv = fmaf(ss[m], v, sv);
    }
    psumH[q * MO + c] = sh;
    psumSH[q * MO + c] = sv;
}

// ---------------- K5: suffix arrays SHS[k]=(SH,SSH); cross-chunk suffix by direct L2 accumulation ----------------
__global__ __launch_bounds__(128) void k_suffix(const float* __restrict__ h,
                                                const int* __restrict__ perm,
                                                const float* __restrict__ s1s,
                                                const float* __restrict__ psumH,
                                                const float* __restrict__ psumSH,
                                                float2* __restrict__ SHS) {
    __shared__ int pi[CH];
    __shared__ float ss[CH];
    const int c = threadIdx.x, q = blockIdx.x;
    if (c < CH) { pi[c] = perm[q * CH + c]; ss[c] = s1s[q * CH + c]; }
    __syncthreads();
    float runH = 0.f, runS = 0.f;
    for (int q2 = q + 1; q2 < NCH; ++q2) {     // psum is 512 KB -> L2-resident
        runH += psumH[q2 * MO + c];
        runS += psumSH[q2 * MO + c];
    }
#pragma unroll 4
    for (int m = CH - 1; m >= 0; --m) {
        int gm = q * CH + m;
        float v = h[(size_t)pi[m] * MO + c];
        runH += v;
        runS = fmaf(ss[m], v, runS);
        SHS[(size_t)gm * MO + c] = make_float2(runH, runS);
    }
    if (q == NCH - 1) SHS[(size_t)NR * MO + c] = make_float2(0.f, 0.f);
}

// ---------------- K6: out[i][c], binary search fused (2 rows per block) ----------------
__global__ __launch_bounds__(256) void k_final(const float2* __restrict__ SHS,
                                               const float* __restrict__ s1s,
                                               const float* __restrict__ s2,
                                               float* __restrict__ out) {
    const int t = threadIdx.x;
    const int i = blockIdx.x * 2 + (t >> 7);
    const int c = t & 127;
    float s2v = s2[i];
    float tv = -s2v;
    int lo = 0, hi = NR;
    while (lo < hi) {                 // uniform per half-block; s1s is 64 KB L2-hot
        int mid = (lo + hi) >> 1;
        if (s1s[mid] < tv) lo = mid + 1; else hi = mid;
    }
    float2 tot = SHS[c];              // suffix from row 0 = totals
    float2 sv  = SHS[(size_t)lo * MO + c];
    out[(size_t)i * MO + c] = ALPHA * fmaf(s2v, tot.x, tot.y)
                            + (1.f - ALPHA) * fmaf(s2v, sv.x, sv.y);
}

extern "C" void kernel_launch(void* const* d_in, const int* in_sizes, int n_in,
                              void* d_out, int out_size, void* d_ws, size_t ws_size,
                              hipStream_t stream) {
    const float* x  = (const float*)d_in[0];
    const float* w  = (const float*)d_in[1];
    const float* a1 = (const float*)d_in[2];
    const float* a2 = (const float*)d_in[3];
    float* out = (float*)d_out;

    float*  ws     = (float*)d_ws;
    float*  h      = ws;                                // NR*MO
    float2* SHS    = (float2*)(h + (size_t)NR * MO);    // (NR+1)*MO float2
    float*  s1     = (float*)(SHS + (size_t)(NR + 1) * MO);
    float*  s2     = s1 + NR;
    float*  s1s    = s2 + NR;
    u64*    keys   = (u64*)(s1s + NR);                  // NR u64
    int*    perm   = (int*)(keys + NR);
    float*  psumH  = (float*)(perm + NR);               // NCH*MO
    float*  psumSH = psumH + NCH * MO;                  // NCH*MO
    // rankPart (NJ*NR ints = 4 MB) aliases SHS (16.8 MB); dead before SHS written in k_suffix
    int*    rankPart = (int*)SHS;

    k_gemm_fused<<<NR / 32, 256, 0, stream>>>(x, w, a1, a2, h, s1, s2, keys);
    k_rank<<<dim3(NR / (256 * RB), NJ), 256, 0, stream>>>(keys, rankPart);
    k_scatter<<<NR / 256, 256, 0, stream>>>(s1, rankPart, s1s, perm);
    k_psum<<<NCH, 128, 0, stream>>>(h, perm, s1s, psumH, psumSH);
    k_suffix<<<NCH, 128, 0, stream>>>(h, perm, s1s, psumH, psumSH, SHS);
    k_final<<<NR / 2, 256, 0, stream>>>(SHS, s1s, s2, out);
}

// Round 7
// 92.135 us; speedup vs baseline: 3.9525x; 1.5814x over previous
//
#include <hip/hip_runtime.h>
#include <stdint.h>

#define NR 16384
#define KI 256
#define MO 128
#define ALPHA 0.01f
#define CH 32             // rows per chunk
#define NCH (NR / CH)     // 512 chunks
#define RB 8              // i-keys per thread in k_rank
#define JT 256            // j-keys staged in LDS per block
#define NJ (NR / JT)      // 64 j-chunks

typedef unsigned long long u64;

// sortable key: monotone float order, index tie-break (rank is a bijection)
static __device__ __forceinline__ u64 sort_key(float f, int j) {
    unsigned u = __float_as_uint(f);
    u ^= ((unsigned)((int)u >> 31)) | 0x80000000u;
    return (((u64)u) << 14) | (unsigned)(j & 0x3FFF);
}

// ---------------- K1: h = x@W^T (32x128 tile, 512 blocks = 2 waves/SIMD) + fused s1,s2,keys ----------------
__global__ __launch_bounds__(256) void k_gemm_fused(const float* __restrict__ x,
                                                    const float* __restrict__ w,
                                                    const float* __restrict__ a1,
                                                    const float* __restrict__ a2,
                                                    float* __restrict__ h,
                                                    float* __restrict__ s1,
                                                    float* __restrict__ s2,
                                                    u64* __restrict__ keys) {
    __shared__ float As[16][36];    // [k][row 0..31]
    __shared__ float Bs[16][132];   // [k][col 0..127]
    const int t = threadIdx.x;
    const int rowBase = blockIdx.x * 32;
    const int tx = t & 15;          // col group: cols tx*8..tx*8+7
    const int ty = t >> 4;          // rows ty*2, ty*2+1
    const int ar = t >> 2, ak = (t & 3) << 2;   // A staging (t<128)
    const int br = t >> 1, bk = (t & 1) << 3;   // B staging
    float acc[2][8] = {};
    for (int k0 = 0; k0 < KI; k0 += 16) {
        float4 av = {};
        if (t < 128) av = *(const float4*)&x[(rowBase + ar) * KI + k0 + ak];
        float4 bv0 = *(const float4*)&w[br * KI + k0 + bk];
        float4 bv1 = *(const float4*)&w[br * KI + k0 + bk + 4];
        __syncthreads();
        if (t < 128) {
            As[ak + 0][ar] = av.x; As[ak + 1][ar] = av.y;
            As[ak + 2][ar] = av.z; As[ak + 3][ar] = av.w;
        }
        Bs[bk + 0][br] = bv0.x; Bs[bk + 1][br] = bv0.y;
        Bs[bk + 2][br] = bv0.z; Bs[bk + 3][br] = bv0.w;
        Bs[bk + 4][br] = bv1.x; Bs[bk + 5][br] = bv1.y;
        Bs[bk + 6][br] = bv1.z; Bs[bk + 7][br] = bv1.w;
        __syncthreads();
#pragma unroll
        for (int k = 0; k < 16; ++k) {
            float2 a2v_ = *(const float2*)&As[k][ty << 1];
            float4 b0 = *(const float4*)&Bs[k][tx << 3];
            float4 b1 = *(const float4*)&Bs[k][(tx << 3) + 4];
            float b[8] = {b0.x, b0.y, b0.z, b0.w, b1.x, b1.y, b1.z, b1.w};
#pragma unroll
            for (int j = 0; j < 8; ++j) {
                acc[0][j] = fmaf(a2v_.x, b[j], acc[0][j]);
                acc[1][j] = fmaf(a2v_.y, b[j], acc[1][j]);
            }
        }
    }
#pragma unroll
    for (int r = 0; r < 2; ++r) {
        float4 st0 = {acc[r][0], acc[r][1], acc[r][2], acc[r][3]};
        float4 st1 = {acc[r][4], acc[r][5], acc[r][6], acc[r][7]};
        float* hp = &h[(size_t)(rowBase + (ty << 1) + r) * MO + (tx << 3)];
        *(float4*)hp = st0;
        *(float4*)(hp + 4) = st1;
    }
    float4 a1lo = *(const float4*)&a1[tx << 3];
    float4 a1hi = *(const float4*)&a1[(tx << 3) + 4];
    float4 a2lo = *(const float4*)&a2[tx << 3];
    float4 a2hi = *(const float4*)&a2[(tx << 3) + 4];
    float a1v[8] = {a1lo.x, a1lo.y, a1lo.z, a1lo.w, a1hi.x, a1hi.y, a1hi.z, a1hi.w};
    float a2v[8] = {a2lo.x, a2lo.y, a2lo.z, a2lo.w, a2hi.x, a2hi.y, a2hi.z, a2hi.w};
#pragma unroll
    for (int r = 0; r < 2; ++r) {
        float p1 = 0.f, p2 = 0.f;
#pragma unroll
        for (int c = 0; c < 8; ++c) {
            p1 = fmaf(acc[r][c], a1v[c], p1);
            p2 = fmaf(acc[r][c], a2v[c], p2);
        }
#pragma unroll
        for (int off = 8; off; off >>= 1) {   // reduce over tx (lane bits 0..3)
            p1 += __shfl_xor(p1, off, 64);
            p2 += __shfl_xor(p2, off, 64);
        }
        if (tx == 0) {
            int row = rowBase + (ty << 1) + r;
            s1[row] = p1;
            s2[row] = p2;
            keys[row] = sort_key(p1, row);
        }
    }
}

// ---------------- K2: rank partials — LDS-broadcast j-keys, 8 i-keys/thread (R3-proven) ----------------
__global__ __launch_bounds__(256) void k_rank(const u64* __restrict__ keys,
                                              int* __restrict__ rankPart) {
    __shared__ u64 sk[JT];
    const int t = threadIdx.x;
    const int ibase = blockIdx.x * (256 * RB);
    const int jbase = blockIdx.y * JT;
    sk[t] = keys[jbase + t];
    u64 ki[RB];
#pragma unroll
    for (int k = 0; k < RB; ++k) ki[k] = keys[ibase + k * 256 + t];
    int cnt[RB] = {};
    __syncthreads();
#pragma unroll 4
    for (int jj = 0; jj < JT; ++jj) {
        u64 kj = sk[jj];                 // uniform addr -> LDS broadcast, conflict-free
#pragma unroll
        for (int k = 0; k < RB; ++k)
            cnt[k] += (kj < ki[k]) ? 1 : 0;
    }
#pragma unroll
    for (int k = 0; k < RB; ++k)
        rankPart[blockIdx.y * NR + ibase + k * 256 + t] = cnt[k];
}

// ---------------- K3: sum partials, scatter into sorted order (R3-proven) ----------------
__global__ __launch_bounds__(256) void k_scatter(const float* __restrict__ s1,
                                                 const int* __restrict__ rankPart,
                                                 float* __restrict__ s1s,
                                                 int* __restrict__ perm) {
    int i = blockIdx.x * 256 + threadIdx.x;
    int r = 0;
#pragma unroll
    for (int p = 0; p < NJ; ++p) r += rankPart[p * NR + i];
    s1s[r] = s1[i];
    perm[r] = i;
}

// ---------------- K4: per-chunk partial sums, 256-thr split-half (8 waves/CU) ----------------
__global__ __launch_bounds__(256) void k_psum(const float* __restrict__ h,
                                              const int* __restrict__ perm,
                                              const float* __restrict__ s1s,
                                              float* __restrict__ psumH,
                                              float* __restrict__ psumSH) {
    __shared__ int pi[CH];
    __shared__ float ss[CH];
    __shared__ float rH[128], rS[128];
    const int t = threadIdx.x, c = t & 127, g = t >> 7, q = blockIdx.x;
    if (t < CH) { pi[t] = perm[q * CH + t]; ss[t] = s1s[q * CH + t]; }
    __syncthreads();
    float pH = 0.f, pS = 0.f;
#pragma unroll
    for (int m = 0; m < 16; ++m) {
        int row = g * 16 + m;
        float v = h[(size_t)pi[row] * MO + c];
        pH += v;
        pS = fmaf(ss[row], v, pS);
    }
    if (g == 1) { rH[c] = pH; rS[c] = pS; }
    __syncthreads();
    if (g == 0) {
        psumH[q * MO + c]  = pH + rH[c];
        psumSH[q * MO + c] = pS + rS[c];
    }
}

// ---------------- K5: exclusive suffix scan over 512 chunk sums (block per column; R3-proven) ----------------
__global__ __launch_bounds__(512) void k_scan(const float* __restrict__ psumH,
                                              const float* __restrict__ psumSH,
                                              float* __restrict__ cSufH,
                                              float* __restrict__ cSufS) {
    __shared__ float bufH[NCH], bufS[NCH];
    const int c = blockIdx.x, q = threadIdx.x;
    float vh = psumH[q * MO + c], vs = psumSH[q * MO + c];
    bufH[q] = vh; bufS[q] = vs;
    __syncthreads();
#pragma unroll
    for (int off = 1; off < NCH; off <<= 1) {
        float ah = 0.f, as = 0.f;
        if (q + off < NCH) { ah = bufH[q + off]; as = bufS[q + off]; }
        __syncthreads();
        bufH[q] += ah; bufS[q] += as;
        __syncthreads();
    }
    cSufH[q * MO + c] = bufH[q] - vh;   // exclusive suffix (chunks > q)
    cSufS[q * MO + c] = bufS[q] - vs;
}

// ---------------- K6: suffix arrays SHS[k]=(SH,SSH), 256-thr split-half ----------------
__global__ __launch_bounds__(256) void k_suffix(const float* __restrict__ h,
                                                const int* __restrict__ perm,
                                                const float* __restrict__ s1s,
                                                const float* __restrict__ cSufH,
                                                const float* __restrict__ cSufS,
                                                float2* __restrict__ SHS) {
    __shared__ int pi[CH];
    __shared__ float ss[CH];
    __shared__ float rH[128], rS[128];
    const int t = threadIdx.x, c = t & 127, g = t >> 7, q = blockIdx.x;
    if (t < CH) { pi[t] = perm[q * CH + t]; ss[t] = s1s[q * CH + t]; }
    __syncthreads();
    float v[16];
#pragma unroll
    for (int m = 0; m < 16; ++m)
        v[m] = h[(size_t)pi[g * 16 + m] * MO + c];
    if (g == 1) {
        float runH = cSufH[q * MO + c], runS = cSufS[q * MO + c];
#pragma unroll
        for (int m = 15; m >= 0; --m) {
            runH += v[m];
            runS = fmaf(ss[16 + m], v[m], runS);
            SHS[(size_t)(q * CH + 16 + m) * MO + c] = make_float2(runH, runS);
        }
        rH[c] = runH; rS[c] = runS;
    }
    __syncthreads();
    if (g == 0) {
        float runH = rH[c], runS = rS[c];
#pragma unroll
        for (int m = 15; m >= 0; --m) {
            runH += v[m];
            runS = fmaf(ss[m], v[m], runS);
            SHS[(size_t)(q * CH + m) * MO + c] = make_float2(runH, runS);
        }
    }
    if (q == NCH - 1 && t < 128) SHS[(size_t)NR * MO + t] = make_float2(0.f, 0.f);
}

// ---------------- K7: out[i][c], binary search fused (2 rows per block; R6-clean) ----------------
__global__ __launch_bounds__(256) void k_final(const float2* __restrict__ SHS,
                                               const float* __restrict__ s1s,
                                               const float* __restrict__ s2,
                                               float* __restrict__ out) {
    const int t = threadIdx.x;
    const int i = blockIdx.x * 2 + (t >> 7);
    const int c = t & 127;
    float s2v = s2[i];
    float tv = -s2v;
    int lo = 0, hi = NR;
    while (lo < hi) {                 // uniform per half-block; s1s is 64 KB L2-hot
        int mid = (lo + hi) >> 1;
        if (s1s[mid] < tv) lo = mid + 1; else hi = mid;
    }
    float2 tot = SHS[c];              // suffix from row 0 = totals
    float2 sv  = SHS[(size_t)lo * MO + c];
    out[(size_t)i * MO + c] = ALPHA * fmaf(s2v, tot.x, tot.y)
                            + (1.f - ALPHA) * fmaf(s2v, sv.x, sv.y);
}

extern "C" void kernel_launch(void* const* d_in, const int* in_sizes, int n_in,
                              void* d_out, int out_size, void* d_ws, size_t ws_size,
                              hipStream_t stream) {
    const float* x  = (const float*)d_in[0];
    const float* w  = (const float*)d_in[1];
    const float* a1 = (const float*)d_in[2];
    const float* a2 = (const float*)d_in[3];
    float* out = (float*)d_out;

    float*  ws     = (float*)d_ws;
    float*  h      = ws;                                // NR*MO
    float2* SHS    = (float2*)(h + (size_t)NR * MO);    // (NR+1)*MO float2
    float*  s1     = (float*)(SHS + (size_t)(NR + 1) * MO);
    float*  s2     = s1 + NR;
    float*  s1s    = s2 + NR;
    u64*    keys   = (u64*)(s1s + NR);                  // NR u64
    int*    perm   = (int*)(keys + NR);
    float*  psumH  = (float*)(perm + NR);               // NCH*MO
    float*  psumSH = psumH + NCH * MO;                  // NCH*MO
    float*  cSufH  = psumSH + NCH * MO;                 // NCH*MO
    float*  cSufS  = cSufH + NCH * MO;                  // NCH*MO
    // rankPart (NJ*NR ints = 4 MB) aliases SHS (16.8 MB); dead before SHS written in k_suffix
    int*    rankPart = (int*)SHS;

    k_gemm_fused<<<NR / 32, 256, 0, stream>>>(x, w, a1, a2, h, s1, s2, keys);
    k_rank<<<dim3(NR / (256 * RB), NJ), 256, 0, stream>>>(keys, rankPart);
    k_scatter<<<NR / 256, 256, 0, stream>>>(s1, rankPart, s1s, perm);
    k_psum<<<NCH, 256, 0, stream>>>(h, perm, s1s, psumH, psumSH);
    k_scan<<<MO, NCH, 0, stream>>>(psumH, psumSH, cSufH, cSufS);
    k_suffix<<<NCH, 256, 0, stream>>>(h, perm, s1s, cSufH, cSufS, SHS);
    k_final<<<NR / 2, 256, 0, stream>>>(SHS, s1s, s2, out);
}